// Round 1
// baseline (26.028 us; speedup 1.0000x reference)
//
#include <hip/hip_runtime.h>

// NGram (tensor2tensor-style), B=2048, L=2048, V=128, n in {1,2}.
// Output row = [hist_n1 (128) | hist_n2 (16384)] as float32, row stride 16512.
//
// Design: 1 block per batch row. LDS histograms:
//   h1: 128 x u32 (counts <= 2048)
//   h2: 16384 bins packed as u16 pairs in 8192 x u32 (counts <= 1024, no carry)
// Then one coalesced streaming write of all 16512 floats (handles zeroing too —
// every output element is written every call; no reliance on prior state).

#define NG_B 2048
#define NG_L 2048
#define NG_V 128
#define NG_NB2 16384           // V*V
#define NG_OUT_ROW (NG_V + NG_NB2)  // 16512
#define NG_THREADS 256

__global__ __launch_bounds__(NG_THREADS)
void NGram_90812788506978_kernel(const int* __restrict__ in, float* __restrict__ out) {
    __shared__ unsigned int h1[NG_V];          // 512 B
    __shared__ unsigned int h2[NG_NB2 / 2];    // 32 KB, packed u16 pairs

    const int tid = threadIdx.x;
    const int b = blockIdx.x;

    // Zero LDS histograms
    for (int i = tid; i < NG_V; i += NG_THREADS) h1[i] = 0u;
    #pragma unroll
    for (int k = 0; k < (NG_NB2 / 2) / NG_THREADS; ++k) h2[tid + k * NG_THREADS] = 0u;
    __syncthreads();

    const int* __restrict__ row = in + (size_t)b * NG_L;
    const int4* __restrict__ row4 = reinterpret_cast<const int4*>(row);

    // 2048 tokens = 512 int4s; 256 threads x 2 int4 each. Coalesced 16B/lane.
    #pragma unroll
    for (int k = 0; k < 2; ++k) {
        const int idx4 = tid + k * NG_THREADS;   // 0..511
        const int4 t = row4[idx4];
        // n=1 unigram counts
        atomicAdd(&h1[t.x], 1u);
        atomicAdd(&h1[t.y], 1u);
        atomicAdd(&h1[t.z], 1u);
        atomicAdd(&h1[t.w], 1u);
        // n=2 bigram windows: (t.x,t.y) and (t.z,t.w); idx = t0*V + t1
        const int i0 = t.x * NG_V + t.y;
        const int i1 = t.z * NG_V + t.w;
        atomicAdd(&h2[i0 >> 1], 1u << (16 * (i0 & 1)));
        atomicAdd(&h2[i1 >> 1], 1u << (16 * (i1 & 1)));
    }
    __syncthreads();

    float* __restrict__ orow = out + (size_t)b * NG_OUT_ROW;

    // n=1 part: 128 floats
    if (tid < NG_V) orow[tid] = (float)h1[tid];

    // n=2 part: 16384 floats, coalesced stores; adjacent lane pairs read the
    // same LDS word (same-address broadcast, conflict-free).
    #pragma unroll
    for (int k = 0; k < NG_NB2 / NG_THREADS; ++k) {
        const int i = tid + k * NG_THREADS;
        const unsigned int w = h2[i >> 1];
        const unsigned int c = (w >> (16 * (i & 1))) & 0xFFFFu;
        orow[NG_V + i] = (float)c;
    }
}

extern "C" void kernel_launch(void* const* d_in, const int* in_sizes, int n_in,
                              void* d_out, int out_size, void* d_ws, size_t ws_size,
                              hipStream_t stream) {
    const int* in = (const int*)d_in[0];
    float* out = (float*)d_out;
    NGram_90812788506978_kernel<<<dim3(NG_B), dim3(NG_THREADS), 0, stream>>>(in, out);
}

// Round 2
// 25.696 us; speedup vs baseline: 1.0129x; 1.0129x over previous
//
#include <hip/hip_runtime.h>

// NGram (tensor2tensor-style), B=2048, L=2048, V=128, n in {1,2}.
// Output row = [hist_n1 (128) | hist_n2 (16384)] as float32, row stride 16512.
//
// Design: 1 block (512 threads) per batch row. LDS histograms:
//   h1: 128 x u32 (counts <= 2048)
//   h2: 16384 bins packed as u16 pairs in 8192 x u32 (counts <= 1024, no carry)
// Epilogue streams all 16512 floats per row with float4 stores (handles
// zeroing too — every output element is written every call).
//
// LDS = 33 KB -> 4 blocks/CU (LDS-limited) x 8 waves = 32 waves/CU (max occ).

#define NG_B 2048
#define NG_L 2048
#define NG_V 128
#define NG_NB2 16384                 // V*V
#define NG_OUT_ROW (NG_V + NG_NB2)   // 16512
#define NG_THREADS 512

__global__ __launch_bounds__(NG_THREADS)
void NGram_90812788506978_kernel(const int* __restrict__ in, float* __restrict__ out) {
    __shared__ unsigned int h1[NG_V];          // 512 B
    __shared__ unsigned int h2[NG_NB2 / 2];    // 32 KB, packed u16 pairs

    const int tid = threadIdx.x;
    const int b = blockIdx.x;

    // Zero LDS histograms (vectorized: ds_write_b128)
    uint4* __restrict__ h2v = reinterpret_cast<uint4*>(h2);
    #pragma unroll
    for (int k = 0; k < (NG_NB2 / 2 / 4) / NG_THREADS; ++k)   // 2048/512 = 4
        h2v[tid + k * NG_THREADS] = make_uint4(0u, 0u, 0u, 0u);
    if (tid < NG_V) h1[tid] = 0u;
    __syncthreads();

    // 2048 tokens = 512 int4s; one coalesced 16B load per thread.
    const int4 t = reinterpret_cast<const int4*>(in + (size_t)b * NG_L)[tid];
    // n=1 unigram counts
    atomicAdd(&h1[t.x], 1u);
    atomicAdd(&h1[t.y], 1u);
    atomicAdd(&h1[t.z], 1u);
    atomicAdd(&h1[t.w], 1u);
    // n=2 non-overlapping bigrams: (t.x,t.y), (t.z,t.w); idx = t0*V + t1
    const int i0 = t.x * NG_V + t.y;
    const int i1 = t.z * NG_V + t.w;
    atomicAdd(&h2[i0 >> 1], 1u << (16 * (i0 & 1)));
    atomicAdd(&h2[i1 >> 1], 1u << (16 * (i1 & 1)));
    __syncthreads();

    float* __restrict__ orow = out + (size_t)b * NG_OUT_ROW;

    // n=1 part: 128 floats as 32 float4 stores (row base is 16B-aligned;
    // 16512*4 bytes row stride keeps every row 16B-aligned).
    if (tid < NG_V / 4) {
        float4 v;
        v.x = (float)h1[4 * tid + 0];
        v.y = (float)h1[4 * tid + 1];
        v.z = (float)h1[4 * tid + 2];
        v.w = (float)h1[4 * tid + 3];
        reinterpret_cast<float4*>(orow)[tid] = v;
    }

    // n=2 part: 16384 floats = 4096 float4s; ds_read_b64 -> unpack 4 u16
    // counts -> global_store_dwordx4. Coalesced 16B/lane stores.
    const uint2* __restrict__ h2p = reinterpret_cast<const uint2*>(h2);
    float4* __restrict__ o2 = reinterpret_cast<float4*>(orow + NG_V);
    #pragma unroll
    for (int k = 0; k < (NG_NB2 / 4) / NG_THREADS; ++k) {     // 4096/512 = 8
        const int i4 = tid + k * NG_THREADS;                  // float4 index
        const uint2 w = h2p[i4];  // word 2*i4 = bins 4i4,4i4+1; word 2*i4+1 = bins 4i4+2,4i4+3
        float4 v;
        v.x = (float)(w.x & 0xFFFFu);
        v.y = (float)(w.x >> 16);
        v.z = (float)(w.y & 0xFFFFu);
        v.w = (float)(w.y >> 16);
        o2[i4] = v;
    }
}

extern "C" void kernel_launch(void* const* d_in, const int* in_sizes, int n_in,
                              void* d_out, int out_size, void* d_ws, size_t ws_size,
                              hipStream_t stream) {
    const int* in = (const int*)d_in[0];
    float* out = (float*)d_out;
    NGram_90812788506978_kernel<<<dim3(NG_B), dim3(NG_THREADS), 0, stream>>>(in, out);
}